// Round 17
// baseline (15.293 us; speedup 1.0000x reference)
//
#include <hip/hip_runtime.h>
#include <limits.h>

// BKT: B=4096 students, T=512 timesteps, K=2048 skills.
// R17: 2 students per block. Plateau at ~14us = walk ~5us + prologue/store/
// launch ~9us; per-student fixed costs (head init, 2 barrier drains, block
// scheduling) and walk exposure are the remaining levers. This version:
//  - NST=2 students/block: LDS = 2x(8KB head + 2KB node) = 20KB exactly ->
//    8 blocks/CU (160KB) x 4 waves = 32 waves/CU; grid 2048.
//  - 4 independent chains interleaved per thread (was 2): walk exposure ~
//    max(4 lens) ~= max(2 lens), so walk time PER STUDENT ~halves.
//  - per-student barrier/init/launch overhead halves.
// Kept: adjacent-pair int2/float2 loads + float2 stores, k0 gathers after
// last barrier (walk hides them), lazy t/g/s, min1/min2 capture (rescan only
// rank>=3), direct-mapped heads, 2 barriers, launch_bounds(256,8).

#define BKT_B 4096
#define BKT_T 512
#define BKT_K 2048
#define BLK   256
#define NST   2               // students per block
#define NCH   (2 * NST)       // chains walked per thread
#define PTR_END 0x3FF

__device__ __forceinline__ float bkt_update(float p, int rbit, float ss,
                                            float gg, float tt) {
  float num, den;
  if (rbit) {                // correct response
    num = p * (1.0f - ss);
    den = num + (1.0f - p) * gg;
  } else {                   // incorrect response
    num = p * ss;
    den = num + (1.0f - p) * (1.0f - gg);
  }
  const float q = num / den; // Bayesian posterior
  return q + (1.0f - q) * tt;// learning transition
}

__global__ __launch_bounds__(BLK, 8) void bkt_kernel(
    const int* __restrict__ skills,
    const float* __restrict__ resp,
    const float* __restrict__ k0,
    const float* __restrict__ tp,
    const float* __restrict__ gp,
    const float* __restrict__ sp,
    float* __restrict__ out) {
  __shared__ int head_s[NST][BKT_K];  // 16KB direct-mapped heads
  __shared__ int node_s[NST][BKT_T];  // 4KB packed {resp bit, prev ptr}

  const int blk = blockIdx.x;
  const int tid = threadIdx.x;

  // coalesced adjacent-pair loads for both students
  int skr[NCH], rbit[NCH];
#pragma unroll
  for (int s = 0; s < NST; ++s) {
    const int base = (blk * NST + s) * BKT_T;
    const int2   skv = ((const int2*)(skills + base))[tid];
    const float2 rrv = ((const float2*)(resp + base))[tid];
    skr[2 * s]     = skv.x;
    skr[2 * s + 1] = skv.y;
    rbit[2 * s]     = rrv.x > 0.5f ? 1 : 0;
    rbit[2 * s + 1] = rrv.y > 0.5f ? 1 : 0;
  }

  // head init: 4096 ints = four int4 stores per thread
  {
    int4* h4 = (int4*)&head_s[0][0];
#pragma unroll
    for (int i = 0; i < NST * BKT_K / 4 / BLK; ++i)   // = 4
      h4[tid + i * BLK] = make_int4(-1, -1, -1, -1);
  }
  __syncthreads();

  // build per-skill linked lists (arrival order arbitrary)
#pragma unroll
  for (int c = 0; c < NCH; ++c) {
    const int s = c >> 1;
    const int t = 2 * tid + (c & 1);
    const int old = atomicExch(&head_s[s][skr[c]], t);
    node_s[s][t] = ((old < 0) ? PTR_END : old) | (rbit[c] << 10);
  }
  __syncthreads();

  // k0 gathers issued after all barriers: walk hides their latency
  float k0v[NCH];
#pragma unroll
  for (int c = 0; c < NCH; ++c)
    k0v[c] = k0[skr[c]];

  // 4-chain interleaved walk with min1/min2 capture
  int headv[NCH], j[NCH], rank[NCH], mn1[NCH], mn2[NCH], nd1[NCH], nd2[NCH];
#pragma unroll
  for (int c = 0; c < NCH; ++c) {
    headv[c] = head_s[c >> 1][skr[c]];
    j[c] = headv[c];
    rank[c] = 0;
    mn1[c] = INT_MAX; mn2[c] = INT_MAX; nd1[c] = 0; nd2[c] = 0;
  }
  while (j[0] >= 0 || j[1] >= 0 || j[2] >= 0 || j[3] >= 0) {
#pragma unroll
    for (int c = 0; c < NCH; ++c) {
      if (j[c] >= 0) {
        const int nd = node_s[c >> 1][j[c]];
        const int t = 2 * tid + (c & 1);
        if (j[c] < t) {
          ++rank[c];
          if (j[c] < mn1[c]) {
            mn2[c] = mn1[c]; nd2[c] = nd1[c]; mn1[c] = j[c]; nd1[c] = nd;
          } else if (j[c] < mn2[c]) {
            mn2[c] = j[c]; nd2[c] = nd;
          }
        }
        const int nx = nd & PTR_END;
        j[c] = (nx == PTR_END) ? -1 : nx;
      }
    }
  }

  // replay each chain (lazy t/g/s gathers; rescan only rank>=3, ~0.3% lanes)
  float pv[NCH];
#pragma unroll
  for (int c = 0; c < NCH; ++c) {
    float p = k0v[c];
    if (rank[c] > 0) {
      const int s_ = skr[c];
      const int t = 2 * tid + (c & 1);
      const float ss = sp[s_];
      const float gg = gp[s_];
      const float tt = tp[s_];
      p = bkt_update(p, (nd1[c] >> 10) & 1, ss, gg, tt);
      if (rank[c] > 1) {
        p = bkt_update(p, (nd2[c] >> 10) & 1, ss, gg, tt);
        int cur = mn2[c];
        for (int rd = 2; rd < rank[c]; ++rd) {
          int best = INT_MAX, bestnode = 0;
          for (int jj = headv[c]; jj >= 0; ) {
            const int nd = node_s[c >> 1][jj];
            if (jj < t && jj > cur && jj < best) { best = jj; bestnode = nd; }
            const int nx = nd & PTR_END;
            jj = (nx == PTR_END) ? -1 : nx;
          }
          p = bkt_update(p, (bestnode >> 10) & 1, ss, gg, tt);
          cur = best;
        }
      }
    }
    pv[c] = p;
  }

  // coalesced float2 stores for both students
#pragma unroll
  for (int s = 0; s < NST; ++s) {
    const int base = (blk * NST + s) * BKT_T;
    ((float2*)(out + base))[tid] = make_float2(pv[2 * s], pv[2 * s + 1]);
  }
}

extern "C" void kernel_launch(void* const* d_in, const int* in_sizes, int n_in,
                              void* d_out, int out_size, void* d_ws, size_t ws_size,
                              hipStream_t stream) {
  const int*   skills = (const int*)d_in[0];
  const float* resp   = (const float*)d_in[1];
  const float* k0     = (const float*)d_in[2];
  const float* tp     = (const float*)d_in[3];
  const float* gp     = (const float*)d_in[4];
  const float* sp     = (const float*)d_in[5];
  float* out = (float*)d_out;

  bkt_kernel<<<BKT_B / NST, BLK, 0, stream>>>(skills, resp, k0, tp, gp, sp, out);
}

// Round 18
// 14.365 us; speedup vs baseline: 1.0646x; 1.0646x over previous
//
#include <hip/hip_runtime.h>
#include <limits.h>

// BKT: B=4096 students, T=512 timesteps, K=2048 skills.
// R18: R17's 2-students-per-block amortization WITHOUT its register
// pressure. R17 regressed (15.3 vs R15's 14.0) -- 4 chains/thread needs
// ~70+ VGPRs vs the 64 pin -> spill. Here: BLK=512, each thread owns ONE
// timestep per student (t = tid for both) = 2 chains/thread = R15's exact
// dual-interleaved walk + register footprint.
//  - geometry: 20KB LDS, 8 waves/block, 4 blocks/CU (wave-limited) = 32
//    waves/CU; grid 2048 (halved launch/scheduling cost).
//  - per-student head-init + barrier-drain costs halve.
// Kept: k0 gathers after last barrier, lazy t/g/s, min1/min2 capture
// (rescan only rank>=3), direct-mapped heads, 2 barriers.

#define BKT_B 4096
#define BKT_T 512
#define BKT_K 2048
#define BLK   512
#define NST   2               // students per block
#define PTR_END 0x3FF

__device__ __forceinline__ float bkt_update(float p, int rbit, float ss,
                                            float gg, float tt) {
  float num, den;
  if (rbit) {                // correct response
    num = p * (1.0f - ss);
    den = num + (1.0f - p) * gg;
  } else {                   // incorrect response
    num = p * ss;
    den = num + (1.0f - p) * (1.0f - gg);
  }
  const float q = num / den; // Bayesian posterior
  return q + (1.0f - q) * tt;// learning transition
}

__global__ __launch_bounds__(BLK, 8) void bkt_kernel(
    const int* __restrict__ skills,
    const float* __restrict__ resp,
    const float* __restrict__ k0,
    const float* __restrict__ tp,
    const float* __restrict__ gp,
    const float* __restrict__ sp,
    float* __restrict__ out) {
  __shared__ int head_s[NST][BKT_K];  // 16KB direct-mapped heads
  __shared__ int node_s[NST][BKT_T];  // 4KB packed {resp bit, prev ptr}

  const int blk = blockIdx.x;
  const int t = threadIdx.x;          // this thread's timestep (both students)
  const int base0 = (blk * NST + 0) * BKT_T;
  const int base1 = (blk * NST + 1) * BKT_T;

  // coalesced scalar loads for both students at timestep t
  const int   sk0 = skills[base0 + t];
  const int   sk1 = skills[base1 + t];
  const float rr0 = resp[base0 + t];
  const float rr1 = resp[base1 + t];

  // head init: 4096 ints / 512 threads = two int4 stores
  {
    int4* h4 = (int4*)&head_s[0][0];
    h4[t] = make_int4(-1, -1, -1, -1);
    h4[t + BLK] = make_int4(-1, -1, -1, -1);
  }
  __syncthreads();

  // build per-skill linked lists (arrival order arbitrary)
  {
    const int old0 = atomicExch(&head_s[0][sk0], t);
    node_s[0][t] = ((old0 < 0) ? PTR_END : old0) | ((rr0 > 0.5f ? 1 : 0) << 10);
    const int old1 = atomicExch(&head_s[1][sk1], t);
    node_s[1][t] = ((old1 < 0) ? PTR_END : old1) | ((rr1 > 0.5f ? 1 : 0) << 10);
  }
  __syncthreads();

  // k0 gathers issued after all barriers: walk hides their latency
  const float k00 = k0[sk0];
  const float k01 = k0[sk1];

  // dual-chain interleaved walk (one chain per student), min1/min2 capture
  const int head0 = head_s[0][sk0];
  const int head1 = head_s[1][sk1];
  int j0 = head0, j1 = head1;
  int rank0 = 0, rank1 = 0;
  int a0 = INT_MAX, b0 = INT_MAX, an0 = 0, bn0 = 0;
  int a1 = INT_MAX, b1 = INT_MAX, an1 = 0, bn1 = 0;
  while ((j0 >= 0) || (j1 >= 0)) {
    if (j0 >= 0) {
      const int nd = node_s[0][j0];
      if (j0 < t) {
        ++rank0;
        if (j0 < a0)      { b0 = a0; bn0 = an0; a0 = j0; an0 = nd; }
        else if (j0 < b0) { b0 = j0; bn0 = nd; }
      }
      const int nx = nd & PTR_END;
      j0 = (nx == PTR_END) ? -1 : nx;
    }
    if (j1 >= 0) {
      const int nd = node_s[1][j1];
      if (j1 < t) {
        ++rank1;
        if (j1 < a1)      { b1 = a1; bn1 = an1; a1 = j1; an1 = nd; }
        else if (j1 < b1) { b1 = j1; bn1 = nd; }
      }
      const int nx = nd & PTR_END;
      j1 = (nx == PTR_END) ? -1 : nx;
    }
  }

  // ---- student 0 replay ----
  float p0 = k00;
  if (rank0 > 0) {
    const float ss = sp[sk0];
    const float gg = gp[sk0];
    const float tt = tp[sk0];
    p0 = bkt_update(p0, (an0 >> 10) & 1, ss, gg, tt);
    if (rank0 > 1) {
      p0 = bkt_update(p0, (bn0 >> 10) & 1, ss, gg, tt);
      int cur = b0;
      for (int rd = 2; rd < rank0; ++rd) {   // rank>=3 only (~0.3% lanes)
        int best = INT_MAX, bestnode = 0;
        for (int j = head0; j >= 0; ) {
          const int nd = node_s[0][j];
          if (j < t && j > cur && j < best) { best = j; bestnode = nd; }
          const int nx = nd & PTR_END;
          j = (nx == PTR_END) ? -1 : nx;
        }
        p0 = bkt_update(p0, (bestnode >> 10) & 1, ss, gg, tt);
        cur = best;
      }
    }
  }
  out[base0 + t] = p0;                 // coalesced store

  // ---- student 1 replay ----
  float p1 = k01;
  if (rank1 > 0) {
    const float ss = sp[sk1];
    const float gg = gp[sk1];
    const float tt = tp[sk1];
    p1 = bkt_update(p1, (an1 >> 10) & 1, ss, gg, tt);
    if (rank1 > 1) {
      p1 = bkt_update(p1, (bn1 >> 10) & 1, ss, gg, tt);
      int cur = b1;
      for (int rd = 2; rd < rank1; ++rd) {
        int best = INT_MAX, bestnode = 0;
        for (int j = head1; j >= 0; ) {
          const int nd = node_s[1][j];
          if (j < t && j > cur && j < best) { best = j; bestnode = nd; }
          const int nx = nd & PTR_END;
          j = (nx == PTR_END) ? -1 : nx;
        }
        p1 = bkt_update(p1, (bestnode >> 10) & 1, ss, gg, tt);
        cur = best;
      }
    }
  }
  out[base1 + t] = p1;                 // coalesced store
}

extern "C" void kernel_launch(void* const* d_in, const int* in_sizes, int n_in,
                              void* d_out, int out_size, void* d_ws, size_t ws_size,
                              hipStream_t stream) {
  const int*   skills = (const int*)d_in[0];
  const float* resp   = (const float*)d_in[1];
  const float* k0     = (const float*)d_in[2];
  const float* tp     = (const float*)d_in[3];
  const float* gp     = (const float*)d_in[4];
  const float* sp     = (const float*)d_in[5];
  float* out = (float*)d_out;

  bkt_kernel<<<BKT_B / NST, BLK, 0, stream>>>(skills, resp, k0, tp, gp, sp, out);
}